// Round 8
// baseline (281.044 us; speedup 1.0000x reference)
//
#include <hip/hip_runtime.h>
#include <hip/hip_bf16.h>
#include <cfloat>

// GATv2 x2 + LayerNorm, B=2 N=512 DIN=32 DH=DOUT=64 H=4. fp32 in/out.
// R8: TI=8 attention (512 blocks, 2/CU), no-max softmax (shift-invariant,
// bounded scores), lane-local denominator, single xl pass.

#define BB   2
#define NN   512
#define DIN  32
#define DH   64
#define HH   4
#define C1   256
#define C2   256
#define TI   8
#define XP   68    // xbuf pitch (floats)
#define LEPS 1e-5f

__device__ __forceinline__ float bf_sum(float v) {
#pragma unroll
    for (int o = 32; o > 0; o >>= 1) v += __shfl_xor(v, o, 64);
    return v;
}

// --- packed mask: bit j of mask64[i*8 + j/64] = (dot(emb_i,emb_j)!=0 || i==j)
__global__ __launch_bounds__(256) void mask_k(const float* __restrict__ emb,
                                              unsigned long long* __restrict__ mask64) {
    __shared__ __align__(16) float s_ei[16][DH];
    __shared__ float ebuf[64][DH + 1];
    int it = blockIdx.x, jq = blockIdx.y;
    int t = threadIdx.x, lane = t & 63, iq = t >> 6;
    {
        int row = t >> 4, d4 = (t & 15) << 2;
        *(float4*)&s_ei[row][d4] = *(const float4*)(emb + (it * 16 + row) * DH + d4);
    }
    for (int jt = 0; jt < 2; jt++) {
        int j0 = jq * 128 + jt * 64;
        __syncthreads();
#pragma unroll
        for (int k = 0; k < 4; k++) {
            int idx = k * 256 + t, jl = idx >> 4, d4 = (idx & 15) << 2;
            float4 v = *(const float4*)(emb + (j0 + jl) * DH + d4);
            ebuf[jl][d4] = v.x; ebuf[jl][d4 + 1] = v.y;
            ebuf[jl][d4 + 2] = v.z; ebuf[jl][d4 + 3] = v.w;
        }
        __syncthreads();
        float acc[4] = {0.f, 0.f, 0.f, 0.f};
        for (int dc = 0; dc < 16; dc++) {
            int d = dc * 4;
            float e0 = ebuf[lane][d], e1 = ebuf[lane][d + 1];
            float e2 = ebuf[lane][d + 2], e3 = ebuf[lane][d + 3];
#pragma unroll
            for (int r = 0; r < 4; r++) {
                float4 iv = *(const float4*)&s_ei[iq * 4 + r][d];
                acc[r] += iv.x * e0 + iv.y * e1 + iv.z * e2 + iv.w * e3;
            }
        }
        int jg = j0 + lane;
#pragma unroll
        for (int r = 0; r < 4; r++) {
            int ig = it * 16 + iq * 4 + r;
            unsigned long long bal = __ballot(acc[r] != 0.f || ig == jg);
            if (lane == 0) mask64[ig * 8 + (j0 >> 6)] = bal;
        }
    }
}

// --- proj1: grid (BB*NN/4, 4 colquads). thread: 2 rows x 1 col, K=32 ---
__global__ __launch_bounds__(256) void proj1_k(const float* __restrict__ x,
        const float* __restrict__ wl, const float* __restrict__ bl,
        const float* __restrict__ wr, const float* __restrict__ br,
        float* __restrict__ xl, float* __restrict__ xr) {
    __shared__ float s_x[4][DIN];
    int t = threadIdx.x, row0 = blockIdx.x * 4, cq = blockIdx.y;
    if (t < 128) s_x[t >> 5][t & 31] = x[(row0 + (t >> 5)) * DIN + (t & 31)];
    __syncthreads();
    int cl = t & 127, half = t >> 7;
    int gc = cq * 128 + cl;
    const float* wbase; float bias; float* obase; int oc;
    if (gc < C1) { wbase = wl + gc; bias = bl[gc]; obase = xl; oc = gc; }
    else         { wbase = wr + gc - C1; bias = br[gc - C1]; obase = xr; oc = gc - C1; }
    int ra = half * 2, rb = ra + 1;
    float a0 = bias, a1 = bias;
#pragma unroll
    for (int k = 0; k < DIN; k++) {
        float wv = wbase[(size_t)k * C1];
        a0 += s_x[ra][k] * wv;
        a1 += s_x[rb][k] * wv;
    }
    obase[(size_t)(row0 + ra) * C1 + oc] = a0;
    obase[(size_t)(row0 + rb) * C1 + oc] = a1;
}

// --- fused LN(g1,be1)+ReLU + proj2. grid (BB*NN/4, 4 colquads). ---
__global__ __launch_bounds__(256) void projln_k(const float* __restrict__ ho,
        const float* __restrict__ g, const float* __restrict__ be,
        const float* __restrict__ wl, const float* __restrict__ bl,
        const float* __restrict__ wr, const float* __restrict__ br,
        float* __restrict__ xl, float* __restrict__ xr) {
    __shared__ __align__(16) float s_h[4][C1];
    int t = threadIdx.x, lane = t & 63, w = t >> 6;
    int row0 = blockIdx.x * 4, cq = blockIdx.y;
    {
        const float* src = ho + (size_t)(row0 + w) * C1;
        float4 v = *(const float4*)(src + (lane << 2));
        float mu = bf_sum(v.x + v.y + v.z + v.w) * (1.f / 256.f);
        float dx = v.x - mu, dy = v.y - mu, dz = v.z - mu, dw = v.w - mu;
        float var = bf_sum(dx * dx + dy * dy + dz * dz + dw * dw) * (1.f / 256.f);
        float rs = rsqrtf(var + LEPS);
        float4 gv = *(const float4*)(g + (lane << 2));
        float4 bv = *(const float4*)(be + (lane << 2));
        float4 y;
        y.x = fmaxf(dx * rs * gv.x + bv.x, 0.f);
        y.y = fmaxf(dy * rs * gv.y + bv.y, 0.f);
        y.z = fmaxf(dz * rs * gv.z + bv.z, 0.f);
        y.w = fmaxf(dw * rs * gv.w + bv.w, 0.f);
        *(float4*)&s_h[w][lane << 2] = y;
    }
    __syncthreads();
    int cl = t & 127, half = t >> 7;
    int gc = cq * 128 + cl;
    const float* wbase; float bias; float* obase; int oc;
    if (gc < C2) { wbase = wl + gc; bias = bl[gc]; obase = xl; oc = gc; }
    else         { wbase = wr + gc - C2; bias = br[gc - C2]; obase = xr; oc = gc - C2; }
    int ra = half * 2, rb = ra + 1;
    float a0 = bias, a1 = bias;
#pragma unroll 8
    for (int k = 0; k < C1; k++) {
        float wv = wbase[(size_t)k * C2];
        a0 += s_h[ra][k] * wv;
        a1 += s_h[rb][k] * wv;
    }
    obase[(size_t)(row0 + ra) * C2 + oc] = a0;
    obase[(size_t)(row0 + rb) * C2 + oc] = a1;
}

// --- GATv2 attention. Block = (i-tile 8, h, b), 256 thr, grid 512 (2/CU). ---
// No-max softmax: p = exp(e) (scores bounded, fp32-safe; softmax shift-inv).
// Wave iq owns rows iq*2, iq*2+1. Lane-local denominator, one bf_sum at end.
__global__ __launch_bounds__(256, 2) void attn_k(const float* __restrict__ xl,
        const float* __restrict__ xr, const float* __restrict__ att,
        const float* __restrict__ bias, const unsigned long long* __restrict__ mask64,
        float* __restrict__ out) {
    __shared__ __align__(16) float s_xr[TI][DH];
    __shared__ __align__(16) float s_att[DH];
    __shared__ __align__(16) float xbuf[64][XP];
    __shared__ __align__(16) float s_p[TI][64];
    __shared__ unsigned long long s_m64[TI * 8];

    int it = blockIdx.x, h = blockIdx.y, b = blockIdx.z;
    int t = threadIdx.x, lane = t & 63, iq = t >> 6;
    int i0 = it * TI;

    if (t < TI * 16) {   // stage xr i-tile (8 rows x 64)
        int row = t >> 4, d4 = (t & 15) << 2;
        *(float4*)&s_xr[row][d4] =
            *(const float4*)(xr + (size_t)(b * NN + i0 + row) * C1 + h * DH + d4);
    }
    if (t < DH) s_att[t] = att[h * DH + t];
    if (t < TI * 8) s_m64[t] = mask64[i0 * 8 + t];
    __syncthreads();

    // wave's 2 xr rows -> registers
    float4 rxr[2][16];
#pragma unroll
    for (int r = 0; r < 2; r++)
#pragma unroll
        for (int dc = 0; dc < 16; dc++)
            rxr[r][dc] = *(const float4*)&s_xr[iq * 2 + r][dc << 2];

    int pidx[4][2];
#pragma unroll
    for (int k = 0; k < 4; k++) {
        int idx = k * 256 + t;
        pidx[k][0] = idx >> 4;            // j-local row
        pidx[k][1] = (idx & 15) << 2;     // d4
    }
    const float* xlbase = xl + (size_t)b * NN * C1 + h * DH;

    float lsum[2] = {0.f, 0.f}, agg[2] = {0.f, 0.f};

    float4 xa[4];
#pragma unroll
    for (int k = 0; k < 4; k++)
        xa[k] = *(const float4*)(xlbase + (size_t)pidx[k][0] * C1 + pidx[k][1]);

    for (int jt = 0; jt < 8; jt++) {
        __syncthreads();
#pragma unroll
        for (int k = 0; k < 4; k++)
            *(float4*)&xbuf[pidx[k][0]][pidx[k][1]] = xa[k];
        __syncthreads();
        if (jt < 7) {
#pragma unroll
            for (int k = 0; k < 4; k++)
                xa[k] = *(const float4*)(xlbase + (size_t)((jt + 1) * 64 + pidx[k][0]) * C1 + pidx[k][1]);
        }

        // ---- scores for j = jt*64 + lane, rows iq*2, iq*2+1 ----
        float acc1[2] = {0.f, 0.f}, acc2[2] = {0.f, 0.f};
#pragma unroll
        for (int dc = 0; dc < 16; dc++) {
            float4 xv = *(const float4*)&xbuf[lane][dc << 2];
            float4 av = *(const float4*)&s_att[dc << 2];
#pragma unroll
            for (int r = 0; r < 2; r++) {
                float z0 = xv.x + rxr[r][dc].x, z1 = xv.y + rxr[r][dc].y;
                float z2 = xv.z + rxr[r][dc].z, z3 = xv.w + rxr[r][dc].w;
                acc1[r] += av.x * z0 + av.y * z1 + av.z * z2 + av.w * z3;
                acc2[r] += av.x * fabsf(z0) + av.y * fabsf(z1)
                         + av.z * fabsf(z2) + av.w * fabsf(z3);
            }
        }
#pragma unroll
        for (int r = 0; r < 2; r++) {
            int il = iq * 2 + r;
            bool live = (s_m64[il * 8 + jt] >> lane) & 1ull;
            // leaky_relu(z) = 0.6z + 0.4|z| for slope 0.2 (linear in att-dot)
            float e = 0.6f * acc1[r] + 0.4f * acc2[r];
            float p = live ? __expf(e) : 0.f;
            lsum[r] += p;
            s_p[il][lane] = p;
        }
        __threadfence_block();

        // ---- aggregate tile: agg[r] (d = lane) += sum_j p_j * xl[j][d] ----
#pragma unroll
        for (int jc = 0; jc < 16; jc++) {
            int j = jc << 2;
            float x0 = xbuf[j][lane], x1 = xbuf[j + 1][lane];
            float x2 = xbuf[j + 2][lane], x3 = xbuf[j + 3][lane];
#pragma unroll
            for (int r = 0; r < 2; r++) {
                float4 p = *(const float4*)&s_p[iq * 2 + r][j];
                agg[r] += p.x * x0 + p.y * x1 + p.z * x2 + p.w * x3;
            }
        }
    }

    float bv = bias[h * DH + lane];
#pragma unroll
    for (int r = 0; r < 2; r++) {
        int il = iq * 2 + r;
        float l = bf_sum(lsum[r]);
        out[(size_t)(b * NN + i0 + il) * C1 + h * DH + lane] = agg[r] / l + bv;
    }
}

// --- final LayerNorm, wave-per-row ---
__global__ __launch_bounds__(256) void ln2_k(const float* __restrict__ in,
        const float* __restrict__ g, const float* __restrict__ be,
        float* __restrict__ outp) {
    int t = threadIdx.x, lane = t & 63, w = t >> 6;
    size_t row = blockIdx.x * 4 + w;
    float4 v = *(const float4*)(in + row * C1 + (lane << 2));
    float mu = bf_sum(v.x + v.y + v.z + v.w) * (1.f / 256.f);
    float dx = v.x - mu, dy = v.y - mu, dz = v.z - mu, dw = v.w - mu;
    float var = bf_sum(dx * dx + dy * dy + dz * dz + dw * dw) * (1.f / 256.f);
    float rs = rsqrtf(var + LEPS);
    float4 gv = *(const float4*)(g + (lane << 2));
    float4 bv = *(const float4*)(be + (lane << 2));
    float4 y;
    y.x = dx * rs * gv.x + bv.x;
    y.y = dy * rs * gv.y + bv.y;
    y.z = dz * rs * gv.z + bv.z;
    y.w = dw * rs * gv.w + bv.w;
    *(float4*)(outp + row * C1 + (lane << 2)) = y;
}

extern "C" void kernel_launch(void* const* d_in, const int* in_sizes, int n_in,
                              void* d_out, int out_size, void* d_ws, size_t ws_size,
                              hipStream_t stream) {
    const float* x    = (const float*)d_in[0];
    const float* emb  = (const float*)d_in[1];
    const float* w1l  = (const float*)d_in[2];
    const float* b1l  = (const float*)d_in[3];
    const float* w1r  = (const float*)d_in[4];
    const float* b1r  = (const float*)d_in[5];
    const float* att1 = (const float*)d_in[6];
    const float* bia1 = (const float*)d_in[7];
    const float* g1   = (const float*)d_in[8];
    const float* be1  = (const float*)d_in[9];
    const float* w2l  = (const float*)d_in[10];
    const float* b2l  = (const float*)d_in[11];
    const float* w2r  = (const float*)d_in[12];
    const float* b2r  = (const float*)d_in[13];
    const float* att2 = (const float*)d_in[14];
    const float* bia2 = (const float*)d_in[15];
    const float* g2   = (const float*)d_in[16];
    const float* be2  = (const float*)d_in[17];

    char* w = (char*)d_ws;
    float* xl                  = (float*)w;              w += (size_t)BB * NN * C1 * 4;
    float* xr                  = (float*)w;              w += (size_t)BB * NN * C1 * 4;
    float* ho                  = (float*)w;              w += (size_t)BB * NN * C1 * 4;
    unsigned long long* mask64 = (unsigned long long*)w; w += (size_t)NN * 8 * 8;

    mask_k<<<dim3(NN / 16, 4), 256, 0, stream>>>(emb, mask64);
    proj1_k<<<dim3(BB * NN / 4, 4), 256, 0, stream>>>(x, w1l, b1l, w1r, b1r, xl, xr);
    attn_k<<<dim3(NN / TI, HH, BB), 256, 0, stream>>>(xl, xr, att1, bia1, mask64, ho);
    projln_k<<<dim3(BB * NN / 4, 4), 256, 0, stream>>>(ho, g1, be1, w2l, b2l, w2r, b2r, xl, xr);
    attn_k<<<dim3(NN / TI, HH, BB), 256, 0, stream>>>(xl, xr, att2, bia2, mask64, ho);
    ln2_k<<<BB * NN / 4, 256, 0, stream>>>(ho, g2, be2, (float*)d_out);
}

// Round 9
// 232.909 us; speedup vs baseline: 1.2067x; 1.2067x over previous
//
#include <hip/hip_runtime.h>
#include <hip/hip_bf16.h>

// GATv2 x2 + LayerNorm, B=2 N=512 DIN=32 DH=DOUT=64 H=4. fp32 in/out.
// R9: leaky split e = [0.6(att.xl_j + att.xr_i)] + [0.4 sum a|z|].
// Linear parts (sl/sr) fused into proj kernels; attn inner loop is
// add+fma(abs) only, all operands via LDS broadcast (no reg hoisting -> no spill).

#define BB   2
#define NN   512
#define DIN  32
#define DH   64
#define HH   4
#define C1   256
#define C2   256
#define TI   8
#define XP   68    // xbuf pitch (floats)
#define LEPS 1e-5f

typedef unsigned long long u64;

__device__ __forceinline__ float bf_sum(float v) {
#pragma unroll
    for (int o = 32; o > 0; o >>= 1) v += __shfl_xor(v, o, 64);
    return v;
}

// --- packed mask: bit j of mask64[i*8 + j/64] = (dot(emb_i,emb_j)!=0 || i==j)
__global__ __launch_bounds__(256) void mask_k(const float* __restrict__ emb,
                                              u64* __restrict__ mask64) {
    __shared__ __align__(16) float s_ei[16][DH];
    __shared__ float ebuf[64][DH + 1];
    int it = blockIdx.x, jq = blockIdx.y;
    int t = threadIdx.x, lane = t & 63, iq = t >> 6;
    {
        int row = t >> 4, d4 = (t & 15) << 2;
        *(float4*)&s_ei[row][d4] = *(const float4*)(emb + (it * 16 + row) * DH + d4);
    }
    for (int jt = 0; jt < 2; jt++) {
        int j0 = jq * 128 + jt * 64;
        __syncthreads();
#pragma unroll
        for (int k = 0; k < 4; k++) {
            int idx = k * 256 + t, jl = idx >> 4, d4 = (idx & 15) << 2;
            float4 v = *(const float4*)(emb + (j0 + jl) * DH + d4);
            ebuf[jl][d4] = v.x; ebuf[jl][d4 + 1] = v.y;
            ebuf[jl][d4 + 2] = v.z; ebuf[jl][d4 + 3] = v.w;
        }
        __syncthreads();
        float acc[4] = {0.f, 0.f, 0.f, 0.f};
        for (int dc = 0; dc < 16; dc++) {
            int d = dc * 4;
            float e0 = ebuf[lane][d], e1 = ebuf[lane][d + 1];
            float e2 = ebuf[lane][d + 2], e3 = ebuf[lane][d + 3];
#pragma unroll
            for (int r = 0; r < 4; r++) {
                float4 iv = *(const float4*)&s_ei[iq * 4 + r][d];
                acc[r] += iv.x * e0 + iv.y * e1 + iv.z * e2 + iv.w * e3;
            }
        }
        int jg = j0 + lane;
#pragma unroll
        for (int r = 0; r < 4; r++) {
            int ig = it * 16 + iq * 4 + r;
            u64 bal = __ballot(acc[r] != 0.f || ig == jg);
            if (lane == 0) mask64[ig * 8 + (j0 >> 6)] = bal;
        }
    }
}

// --- proj1 + fused sl/sr: grid (BB*NN/4, 4 colquads), thread: 2 rows x 1 col ---
// sl[(h*BB+b)*NN + i] = 0.6 * att_h . xl[b,i,h,:]   (sr analogous from xr)
__global__ __launch_bounds__(256) void proj1_k(const float* __restrict__ x,
        const float* __restrict__ wl, const float* __restrict__ bl,
        const float* __restrict__ wr, const float* __restrict__ br,
        const float* __restrict__ att,
        float* __restrict__ xl, float* __restrict__ xr,
        float* __restrict__ sl, float* __restrict__ sr) {
    __shared__ float s_x[4][DIN];
    int t = threadIdx.x, lane = t & 63, row0 = blockIdx.x * 4, cq = blockIdx.y;
    if (t < 128) s_x[t >> 5][t & 31] = x[(row0 + (t >> 5)) * DIN + (t & 31)];
    __syncthreads();
    int cl = t & 127, half = t >> 7;
    int gc = cq * 128 + cl;
    const float* wbase; float bias; float* obase; float* sdst; int oc;
    if (gc < C1) { wbase = wl + gc; bias = bl[gc]; obase = xl; sdst = sl; oc = gc; }
    else         { wbase = wr + gc - C1; bias = br[gc - C1]; obase = xr; sdst = sr; oc = gc - C1; }
    int ra = half * 2, rb = ra + 1;
    float a0 = bias, a1 = bias;
#pragma unroll
    for (int k = 0; k < DIN; k++) {
        float wv = wbase[(size_t)k * C1];
        a0 += s_x[ra][k] * wv;
        a1 += s_x[rb][k] * wv;
    }
    obase[(size_t)(row0 + ra) * C1 + oc] = a0;
    obase[(size_t)(row0 + rb) * C1 + oc] = a1;
    float attv = att[oc];
    float s0 = bf_sum(attv * a0) * 0.6f;
    float s1 = bf_sum(attv * a1) * 0.6f;
    if (lane == 0) {
        int h = oc >> 6;
        int rwa = row0 + ra, rwb = row0 + rb;
        sdst[(h * BB + (rwa >> 9)) * NN + (rwa & 511)] = s0;
        sdst[(h * BB + (rwb >> 9)) * NN + (rwb & 511)] = s1;
    }
}

// --- fused LN(g1,be1)+ReLU + proj2 + sl/sr. grid (BB*NN/4, 4 colquads) ---
__global__ __launch_bounds__(256) void projln_k(const float* __restrict__ ho,
        const float* __restrict__ g, const float* __restrict__ be,
        const float* __restrict__ wl, const float* __restrict__ bl,
        const float* __restrict__ wr, const float* __restrict__ br,
        const float* __restrict__ att,
        float* __restrict__ xl, float* __restrict__ xr,
        float* __restrict__ sl, float* __restrict__ sr) {
    __shared__ __align__(16) float s_h[4][C1];
    int t = threadIdx.x, lane = t & 63, w = t >> 6;
    int row0 = blockIdx.x * 4, cq = blockIdx.y;
    {
        const float* src = ho + (size_t)(row0 + w) * C1;
        float4 v = *(const float4*)(src + (lane << 2));
        float mu = bf_sum(v.x + v.y + v.z + v.w) * (1.f / 256.f);
        float dx = v.x - mu, dy = v.y - mu, dz = v.z - mu, dw = v.w - mu;
        float var = bf_sum(dx * dx + dy * dy + dz * dz + dw * dw) * (1.f / 256.f);
        float rs = rsqrtf(var + LEPS);
        float4 gv = *(const float4*)(g + (lane << 2));
        float4 bv = *(const float4*)(be + (lane << 2));
        float4 y;
        y.x = fmaxf(dx * rs * gv.x + bv.x, 0.f);
        y.y = fmaxf(dy * rs * gv.y + bv.y, 0.f);
        y.z = fmaxf(dz * rs * gv.z + bv.z, 0.f);
        y.w = fmaxf(dw * rs * gv.w + bv.w, 0.f);
        *(float4*)&s_h[w][lane << 2] = y;
    }
    __syncthreads();
    int cl = t & 127, half = t >> 7;
    int gc = cq * 128 + cl;
    const float* wbase; float bias; float* obase; float* sdst; int oc;
    if (gc < C2) { wbase = wl + gc; bias = bl[gc]; obase = xl; sdst = sl; oc = gc; }
    else         { wbase = wr + gc - C2; bias = br[gc - C2]; obase = xr; sdst = sr; oc = gc - C2; }
    int ra = half * 2, rb = ra + 1;
    float a0 = bias, a1 = bias;
#pragma unroll 8
    for (int k = 0; k < C1; k++) {
        float wv = wbase[(size_t)k * C2];
        a0 += s_h[ra][k] * wv;
        a1 += s_h[rb][k] * wv;
    }
    obase[(size_t)(row0 + ra) * C2 + oc] = a0;
    obase[(size_t)(row0 + rb) * C2 + oc] = a1;
    float attv = att[oc];
    float s0 = bf_sum(attv * a0) * 0.6f;
    float s1 = bf_sum(attv * a1) * 0.6f;
    if (lane == 0) {
        int h = oc >> 6;
        int rwa = row0 + ra, rwb = row0 + rb;
        sdst[(h * BB + (rwa >> 9)) * NN + (rwa & 511)] = s0;
        sdst[(h * BB + (rwb >> 9)) * NN + (rwb & 511)] = s1;
    }
}

// --- GATv2 attention. Block = (i-tile 8, h, b), 256 thr, grid 512 (2/CU). ---
// e = sl'[j] + sr'[i] + sum_d (0.4 a_d)|xl_jd + xr_id|; p = exp(e) (no-max,
// shift-invariant + bounded scores). Wave iq owns rows iq*2, iq*2+1.
__global__ __launch_bounds__(256, 2) void attn_k(const float* __restrict__ xl,
        const float* __restrict__ xr, const float* __restrict__ att,
        const float* __restrict__ bias, const u64* __restrict__ mask64,
        const float* __restrict__ sl, const float* __restrict__ sr,
        float* __restrict__ out) {
    __shared__ __align__(16) float s_xr[TI][DH];
    __shared__ __align__(16) float s_att[DH];     // prescaled by 0.4
    __shared__ __align__(16) float xbuf[64][XP];
    __shared__ __align__(16) float s_p[TI][64];
    __shared__ __align__(16) float s_sl[NN];      // prescaled by 0.6
    __shared__ float s_sr[TI];                    // prescaled by 0.6
    __shared__ u64 s_m64[TI * 8];

    int it = blockIdx.x, h = blockIdx.y, b = blockIdx.z;
    int t = threadIdx.x, lane = t & 63, iq = t >> 6;
    int i0 = it * TI;

    if (t < TI * 16) {   // 8 xr rows
        int row = t >> 4, d4 = (t & 15) << 2;
        *(float4*)&s_xr[row][d4] =
            *(const float4*)(xr + (size_t)(b * NN + i0 + row) * C1 + h * DH + d4);
    }
    if (t < DH) s_att[t] = att[h * DH + t] * 0.4f;
    if (t < TI) s_sr[t] = sr[(h * BB + b) * NN + i0 + t];
    if (t < TI * 8) s_m64[t] = mask64[(i0 + (t >> 3)) * 8 + (t & 7)];
    if (t < 128) *(float4*)&s_sl[t << 2] = *(const float4*)(sl + (h * BB + b) * NN + (t << 2));
    __syncthreads();

    float rsr[2] = { s_sr[iq * 2], s_sr[iq * 2 + 1] };

    int pidx[4][2];
#pragma unroll
    for (int k = 0; k < 4; k++) {
        int idx = k * 256 + t;
        pidx[k][0] = idx >> 4;            // j-local row
        pidx[k][1] = (idx & 15) << 2;     // d4
    }
    const float* xlbase = xl + (size_t)b * NN * C1 + h * DH;

    float lsum[2] = {0.f, 0.f}, agg[2] = {0.f, 0.f};

    float4 xa[4];
#pragma unroll
    for (int k = 0; k < 4; k++)
        xa[k] = *(const float4*)(xlbase + (size_t)pidx[k][0] * C1 + pidx[k][1]);

    for (int jt = 0; jt < 8; jt++) {
        __syncthreads();
#pragma unroll
        for (int k = 0; k < 4; k++)
            *(float4*)&xbuf[pidx[k][0]][pidx[k][1]] = xa[k];
        __syncthreads();
        if (jt < 7) {
#pragma unroll
            for (int k = 0; k < 4; k++)
                xa[k] = *(const float4*)(xlbase + (size_t)((jt + 1) * 64 + pidx[k][0]) * C1 + pidx[k][1]);
        }

        // ---- |.|-scores for j = jt*64 + lane, rows iq*2, iq*2+1 ----
        float acc2[2] = {0.f, 0.f};
#pragma unroll
        for (int dc = 0; dc < 16; dc++) {
            float4 xv = *(const float4*)&xbuf[lane][dc << 2];
            float4 av = *(const float4*)&s_att[dc << 2];
#pragma unroll
            for (int r = 0; r < 2; r++) {
                float4 rv = *(const float4*)&s_xr[iq * 2 + r][dc << 2];
                float z0 = xv.x + rv.x, z1 = xv.y + rv.y;
                float z2 = xv.z + rv.z, z3 = xv.w + rv.w;
                acc2[r] = fmaf(av.x, fabsf(z0), acc2[r]);
                acc2[r] = fmaf(av.y, fabsf(z1), acc2[r]);
                acc2[r] = fmaf(av.z, fabsf(z2), acc2[r]);
                acc2[r] = fmaf(av.w, fabsf(z3), acc2[r]);
            }
        }
        int jg = jt * 64 + lane;
        float slv = s_sl[jg];
#pragma unroll
        for (int r = 0; r < 2; r++) {
            int il = iq * 2 + r;
            bool live = (s_m64[il * 8 + jt] >> lane) & 1ull;
            float e = slv + rsr[r] + acc2[r];
            float p = live ? __expf(e) : 0.f;
            lsum[r] += p;
            s_p[il][lane] = p;
        }
        __threadfence_block();

        // ---- aggregate tile: agg[r] (d = lane) += sum_j p_j * xl[j][d] ----
#pragma unroll
        for (int jc = 0; jc < 16; jc++) {
            int j = jc << 2;
            float x0 = xbuf[j][lane], x1 = xbuf[j + 1][lane];
            float x2 = xbuf[j + 2][lane], x3 = xbuf[j + 3][lane];
#pragma unroll
            for (int r = 0; r < 2; r++) {
                float4 p = *(const float4*)&s_p[iq * 2 + r][j];
                agg[r] += p.x * x0 + p.y * x1 + p.z * x2 + p.w * x3;
            }
        }
    }

    float bv = bias[h * DH + lane];
#pragma unroll
    for (int r = 0; r < 2; r++) {
        int il = iq * 2 + r;
        float l = bf_sum(lsum[r]);
        out[(size_t)(b * NN + i0 + il) * C1 + h * DH + lane] = agg[r] / l + bv;
    }
}

// --- final LayerNorm, wave-per-row ---
__global__ __launch_bounds__(256) void ln2_k(const float* __restrict__ in,
        const float* __restrict__ g, const float* __restrict__ be,
        float* __restrict__ outp) {
    int t = threadIdx.x, lane = t & 63, w = t >> 6;
    size_t row = blockIdx.x * 4 + w;
    float4 v = *(const float4*)(in + row * C1 + (lane << 2));
    float mu = bf_sum(v.x + v.y + v.z + v.w) * (1.f / 256.f);
    float dx = v.x - mu, dy = v.y - mu, dz = v.z - mu, dw = v.w - mu;
    float var = bf_sum(dx * dx + dy * dy + dz * dz + dw * dw) * (1.f / 256.f);
    float rs = rsqrtf(var + LEPS);
    float4 gv = *(const float4*)(g + (lane << 2));
    float4 bv = *(const float4*)(be + (lane << 2));
    float4 y;
    y.x = dx * rs * gv.x + bv.x;
    y.y = dy * rs * gv.y + bv.y;
    y.z = dz * rs * gv.z + bv.z;
    y.w = dw * rs * gv.w + bv.w;
    *(float4*)(outp + row * C1 + (lane << 2)) = y;
}

extern "C" void kernel_launch(void* const* d_in, const int* in_sizes, int n_in,
                              void* d_out, int out_size, void* d_ws, size_t ws_size,
                              hipStream_t stream) {
    const float* x    = (const float*)d_in[0];
    const float* emb  = (const float*)d_in[1];
    const float* w1l  = (const float*)d_in[2];
    const float* b1l  = (const float*)d_in[3];
    const float* w1r  = (const float*)d_in[4];
    const float* b1r  = (const float*)d_in[5];
    const float* att1 = (const float*)d_in[6];
    const float* bia1 = (const float*)d_in[7];
    const float* g1   = (const float*)d_in[8];
    const float* be1  = (const float*)d_in[9];
    const float* w2l  = (const float*)d_in[10];
    const float* b2l  = (const float*)d_in[11];
    const float* w2r  = (const float*)d_in[12];
    const float* b2r  = (const float*)d_in[13];
    const float* att2 = (const float*)d_in[14];
    const float* bia2 = (const float*)d_in[15];
    const float* g2   = (const float*)d_in[16];
    const float* be2  = (const float*)d_in[17];

    char* w = (char*)d_ws;
    float* xl    = (float*)w; w += (size_t)BB * NN * C1 * 4;
    float* xr    = (float*)w; w += (size_t)BB * NN * C1 * 4;
    float* ho    = (float*)w; w += (size_t)BB * NN * C1 * 4;
    u64* mask64  = (u64*)w;   w += (size_t)NN * 8 * 8;
    float* sl    = (float*)w; w += (size_t)HH * BB * NN * 4;
    float* sr    = (float*)w; w += (size_t)HH * BB * NN * 4;

    mask_k<<<dim3(NN / 16, 4), 256, 0, stream>>>(emb, mask64);
    proj1_k<<<dim3(BB * NN / 4, 4), 256, 0, stream>>>(x, w1l, b1l, w1r, b1r, att1, xl, xr, sl, sr);
    attn_k<<<dim3(NN / TI, HH, BB), 256, 0, stream>>>(xl, xr, att1, bia1, mask64, sl, sr, ho);
    projln_k<<<dim3(BB * NN / 4, 4), 256, 0, stream>>>(ho, g1, be1, w2l, b2l, w2r, b2r, att2, xl, xr, sl, sr);
    attn_k<<<dim3(NN / TI, HH, BB), 256, 0, stream>>>(xl, xr, att2, bia2, mask64, sl, sr, ho);
    ln2_k<<<BB * NN / 4, 256, 0, stream>>>(ho, g2, be2, (float*)d_out);
}

// Round 10
// 217.820 us; speedup vs baseline: 1.2903x; 1.0693x over previous
//
#include <hip/hip_runtime.h>
#include <hip/hip_bf16.h>

// GATv2 x2 + LayerNorm, B=2 N=512 DIN=32 DH=DOUT=64 H=4. fp32 in/out.
// R10: identical to R9 except attn_k __launch_bounds__(256) — the (256,2)
// variant made the compiler cap VGPRs at 128 and spill ~143 MB/dispatch
// to scratch (R8/R9 counters). Register demand ~70 -> fits 2 blk/CU free.

#define BB   2
#define NN   512
#define DIN  32
#define DH   64
#define HH   4
#define C1   256
#define C2   256
#define TI   8
#define XP   68    // xbuf pitch (floats)
#define LEPS 1e-5f

typedef unsigned long long u64;

__device__ __forceinline__ float bf_sum(float v) {
#pragma unroll
    for (int o = 32; o > 0; o >>= 1) v += __shfl_xor(v, o, 64);
    return v;
}

// --- packed mask: bit j of mask64[i*8 + j/64] = (dot(emb_i,emb_j)!=0 || i==j)
__global__ __launch_bounds__(256) void mask_k(const float* __restrict__ emb,
                                              u64* __restrict__ mask64) {
    __shared__ __align__(16) float s_ei[16][DH];
    __shared__ float ebuf[64][DH + 1];
    int it = blockIdx.x, jq = blockIdx.y;
    int t = threadIdx.x, lane = t & 63, iq = t >> 6;
    {
        int row = t >> 4, d4 = (t & 15) << 2;
        *(float4*)&s_ei[row][d4] = *(const float4*)(emb + (it * 16 + row) * DH + d4);
    }
    for (int jt = 0; jt < 2; jt++) {
        int j0 = jq * 128 + jt * 64;
        __syncthreads();
#pragma unroll
        for (int k = 0; k < 4; k++) {
            int idx = k * 256 + t, jl = idx >> 4, d4 = (idx & 15) << 2;
            float4 v = *(const float4*)(emb + (j0 + jl) * DH + d4);
            ebuf[jl][d4] = v.x; ebuf[jl][d4 + 1] = v.y;
            ebuf[jl][d4 + 2] = v.z; ebuf[jl][d4 + 3] = v.w;
        }
        __syncthreads();
        float acc[4] = {0.f, 0.f, 0.f, 0.f};
        for (int dc = 0; dc < 16; dc++) {
            int d = dc * 4;
            float e0 = ebuf[lane][d], e1 = ebuf[lane][d + 1];
            float e2 = ebuf[lane][d + 2], e3 = ebuf[lane][d + 3];
#pragma unroll
            for (int r = 0; r < 4; r++) {
                float4 iv = *(const float4*)&s_ei[iq * 4 + r][d];
                acc[r] += iv.x * e0 + iv.y * e1 + iv.z * e2 + iv.w * e3;
            }
        }
        int jg = j0 + lane;
#pragma unroll
        for (int r = 0; r < 4; r++) {
            int ig = it * 16 + iq * 4 + r;
            u64 bal = __ballot(acc[r] != 0.f || ig == jg);
            if (lane == 0) mask64[ig * 8 + (j0 >> 6)] = bal;
        }
    }
}

// --- proj1 + fused sl/sr: grid (BB*NN/4, 4 colquads), thread: 2 rows x 1 col ---
// sl[(h*BB+b)*NN + i] = 0.6 * att_h . xl[b,i,h,:]   (sr analogous from xr)
__global__ __launch_bounds__(256) void proj1_k(const float* __restrict__ x,
        const float* __restrict__ wl, const float* __restrict__ bl,
        const float* __restrict__ wr, const float* __restrict__ br,
        const float* __restrict__ att,
        float* __restrict__ xl, float* __restrict__ xr,
        float* __restrict__ sl, float* __restrict__ sr) {
    __shared__ float s_x[4][DIN];
    int t = threadIdx.x, lane = t & 63, row0 = blockIdx.x * 4, cq = blockIdx.y;
    if (t < 128) s_x[t >> 5][t & 31] = x[(row0 + (t >> 5)) * DIN + (t & 31)];
    __syncthreads();
    int cl = t & 127, half = t >> 7;
    int gc = cq * 128 + cl;
    const float* wbase; float bias; float* obase; float* sdst; int oc;
    if (gc < C1) { wbase = wl + gc; bias = bl[gc]; obase = xl; sdst = sl; oc = gc; }
    else         { wbase = wr + gc - C1; bias = br[gc - C1]; obase = xr; sdst = sr; oc = gc - C1; }
    int ra = half * 2, rb = ra + 1;
    float a0 = bias, a1 = bias;
#pragma unroll
    for (int k = 0; k < DIN; k++) {
        float wv = wbase[(size_t)k * C1];
        a0 += s_x[ra][k] * wv;
        a1 += s_x[rb][k] * wv;
    }
    obase[(size_t)(row0 + ra) * C1 + oc] = a0;
    obase[(size_t)(row0 + rb) * C1 + oc] = a1;
    float attv = att[oc];
    float s0 = bf_sum(attv * a0) * 0.6f;
    float s1 = bf_sum(attv * a1) * 0.6f;
    if (lane == 0) {
        int h = oc >> 6;
        int rwa = row0 + ra, rwb = row0 + rb;
        sdst[(h * BB + (rwa >> 9)) * NN + (rwa & 511)] = s0;
        sdst[(h * BB + (rwb >> 9)) * NN + (rwb & 511)] = s1;
    }
}

// --- fused LN(g1,be1)+ReLU + proj2 + sl/sr. grid (BB*NN/4, 4 colquads) ---
__global__ __launch_bounds__(256) void projln_k(const float* __restrict__ ho,
        const float* __restrict__ g, const float* __restrict__ be,
        const float* __restrict__ wl, const float* __restrict__ bl,
        const float* __restrict__ wr, const float* __restrict__ br,
        const float* __restrict__ att,
        float* __restrict__ xl, float* __restrict__ xr,
        float* __restrict__ sl, float* __restrict__ sr) {
    __shared__ __align__(16) float s_h[4][C1];
    int t = threadIdx.x, lane = t & 63, w = t >> 6;
    int row0 = blockIdx.x * 4, cq = blockIdx.y;
    {
        const float* src = ho + (size_t)(row0 + w) * C1;
        float4 v = *(const float4*)(src + (lane << 2));
        float mu = bf_sum(v.x + v.y + v.z + v.w) * (1.f / 256.f);
        float dx = v.x - mu, dy = v.y - mu, dz = v.z - mu, dw = v.w - mu;
        float var = bf_sum(dx * dx + dy * dy + dz * dz + dw * dw) * (1.f / 256.f);
        float rs = rsqrtf(var + LEPS);
        float4 gv = *(const float4*)(g + (lane << 2));
        float4 bv = *(const float4*)(be + (lane << 2));
        float4 y;
        y.x = fmaxf(dx * rs * gv.x + bv.x, 0.f);
        y.y = fmaxf(dy * rs * gv.y + bv.y, 0.f);
        y.z = fmaxf(dz * rs * gv.z + bv.z, 0.f);
        y.w = fmaxf(dw * rs * gv.w + bv.w, 0.f);
        *(float4*)&s_h[w][lane << 2] = y;
    }
    __syncthreads();
    int cl = t & 127, half = t >> 7;
    int gc = cq * 128 + cl;
    const float* wbase; float bias; float* obase; float* sdst; int oc;
    if (gc < C2) { wbase = wl + gc; bias = bl[gc]; obase = xl; sdst = sl; oc = gc; }
    else         { wbase = wr + gc - C2; bias = br[gc - C2]; obase = xr; sdst = sr; oc = gc - C2; }
    int ra = half * 2, rb = ra + 1;
    float a0 = bias, a1 = bias;
#pragma unroll 8
    for (int k = 0; k < C1; k++) {
        float wv = wbase[(size_t)k * C2];
        a0 += s_h[ra][k] * wv;
        a1 += s_h[rb][k] * wv;
    }
    obase[(size_t)(row0 + ra) * C2 + oc] = a0;
    obase[(size_t)(row0 + rb) * C2 + oc] = a1;
    float attv = att[oc];
    float s0 = bf_sum(attv * a0) * 0.6f;
    float s1 = bf_sum(attv * a1) * 0.6f;
    if (lane == 0) {
        int h = oc >> 6;
        int rwa = row0 + ra, rwb = row0 + rb;
        sdst[(h * BB + (rwa >> 9)) * NN + (rwa & 511)] = s0;
        sdst[(h * BB + (rwb >> 9)) * NN + (rwb & 511)] = s1;
    }
}

// --- GATv2 attention. Block = (i-tile 8, h, b), 256 thr, grid 512 (2/CU). ---
// e = sl'[j] + sr'[i] + sum_d (0.4 a_d)|xl_jd + xr_id|; p = exp(e) (no-max,
// shift-invariant + bounded scores). Wave iq owns rows iq*2, iq*2+1.
// NOTE: no min-occupancy arg — (256,2) forced a 128-VGPR cap + scratch spill.
__global__ __launch_bounds__(256) void attn_k(const float* __restrict__ xl,
        const float* __restrict__ xr, const float* __restrict__ att,
        const float* __restrict__ bias, const u64* __restrict__ mask64,
        const float* __restrict__ sl, const float* __restrict__ sr,
        float* __restrict__ out) {
    __shared__ __align__(16) float s_xr[TI][DH];
    __shared__ __align__(16) float s_att[DH];     // prescaled by 0.4
    __shared__ __align__(16) float xbuf[64][XP];
    __shared__ __align__(16) float s_p[TI][64];
    __shared__ __align__(16) float s_sl[NN];      // prescaled by 0.6
    __shared__ float s_sr[TI];                    // prescaled by 0.6
    __shared__ u64 s_m64[TI * 8];

    int it = blockIdx.x, h = blockIdx.y, b = blockIdx.z;
    int t = threadIdx.x, lane = t & 63, iq = t >> 6;
    int i0 = it * TI;

    if (t < TI * 16) {   // 8 xr rows
        int row = t >> 4, d4 = (t & 15) << 2;
        *(float4*)&s_xr[row][d4] =
            *(const float4*)(xr + (size_t)(b * NN + i0 + row) * C1 + h * DH + d4);
    }
    if (t < DH) s_att[t] = att[h * DH + t] * 0.4f;
    if (t < TI) s_sr[t] = sr[(h * BB + b) * NN + i0 + t];
    if (t < TI * 8) s_m64[t] = mask64[(i0 + (t >> 3)) * 8 + (t & 7)];
    if (t < 128) *(float4*)&s_sl[t << 2] = *(const float4*)(sl + (h * BB + b) * NN + (t << 2));
    __syncthreads();

    float rsr[2] = { s_sr[iq * 2], s_sr[iq * 2 + 1] };

    int pidx[4][2];
#pragma unroll
    for (int k = 0; k < 4; k++) {
        int idx = k * 256 + t;
        pidx[k][0] = idx >> 4;            // j-local row
        pidx[k][1] = (idx & 15) << 2;     // d4
    }
    const float* xlbase = xl + (size_t)b * NN * C1 + h * DH;

    float lsum[2] = {0.f, 0.f}, agg[2] = {0.f, 0.f};

    float4 xa[4];
#pragma unroll
    for (int k = 0; k < 4; k++)
        xa[k] = *(const float4*)(xlbase + (size_t)pidx[k][0] * C1 + pidx[k][1]);

    for (int jt = 0; jt < 8; jt++) {
        __syncthreads();
#pragma unroll
        for (int k = 0; k < 4; k++)
            *(float4*)&xbuf[pidx[k][0]][pidx[k][1]] = xa[k];
        __syncthreads();
        if (jt < 7) {
#pragma unroll
            for (int k = 0; k < 4; k++)
                xa[k] = *(const float4*)(xlbase + (size_t)((jt + 1) * 64 + pidx[k][0]) * C1 + pidx[k][1]);
        }

        // ---- |.|-scores for j = jt*64 + lane, rows iq*2, iq*2+1 ----
        float acc2[2] = {0.f, 0.f};
#pragma unroll
        for (int dc = 0; dc < 16; dc++) {
            float4 xv = *(const float4*)&xbuf[lane][dc << 2];
            float4 av = *(const float4*)&s_att[dc << 2];
#pragma unroll
            for (int r = 0; r < 2; r++) {
                float4 rv = *(const float4*)&s_xr[iq * 2 + r][dc << 2];
                float z0 = xv.x + rv.x, z1 = xv.y + rv.y;
                float z2 = xv.z + rv.z, z3 = xv.w + rv.w;
                acc2[r] = fmaf(av.x, fabsf(z0), acc2[r]);
                acc2[r] = fmaf(av.y, fabsf(z1), acc2[r]);
                acc2[r] = fmaf(av.z, fabsf(z2), acc2[r]);
                acc2[r] = fmaf(av.w, fabsf(z3), acc2[r]);
            }
        }
        int jg = jt * 64 + lane;
        float slv = s_sl[jg];
#pragma unroll
        for (int r = 0; r < 2; r++) {
            int il = iq * 2 + r;
            bool live = (s_m64[il * 8 + jt] >> lane) & 1ull;
            float e = slv + rsr[r] + acc2[r];
            float p = live ? __expf(e) : 0.f;
            lsum[r] += p;
            s_p[il][lane] = p;
        }
        __threadfence_block();

        // ---- aggregate tile: agg[r] (d = lane) += sum_j p_j * xl[j][d] ----
#pragma unroll
        for (int jc = 0; jc < 16; jc++) {
            int j = jc << 2;
            float x0 = xbuf[j][lane], x1 = xbuf[j + 1][lane];
            float x2 = xbuf[j + 2][lane], x3 = xbuf[j + 3][lane];
#pragma unroll
            for (int r = 0; r < 2; r++) {
                float4 p = *(const float4*)&s_p[iq * 2 + r][j];
                agg[r] += p.x * x0 + p.y * x1 + p.z * x2 + p.w * x3;
            }
        }
    }

    float bv = bias[h * DH + lane];
#pragma unroll
    for (int r = 0; r < 2; r++) {
        int il = iq * 2 + r;
        float l = bf_sum(lsum[r]);
        out[(size_t)(b * NN + i0 + il) * C1 + h * DH + lane] = agg[r] / l + bv;
    }
}

// --- final LayerNorm, wave-per-row ---
__global__ __launch_bounds__(256) void ln2_k(const float* __restrict__ in,
        const float* __restrict__ g, const float* __restrict__ be,
        float* __restrict__ outp) {
    int t = threadIdx.x, lane = t & 63, w = t >> 6;
    size_t row = blockIdx.x * 4 + w;
    float4 v = *(const float4*)(in + row * C1 + (lane << 2));
    float mu = bf_sum(v.x + v.y + v.z + v.w) * (1.f / 256.f);
    float dx = v.x - mu, dy = v.y - mu, dz = v.z - mu, dw = v.w - mu;
    float var = bf_sum(dx * dx + dy * dy + dz * dz + dw * dw) * (1.f / 256.f);
    float rs = rsqrtf(var + LEPS);
    float4 gv = *(const float4*)(g + (lane << 2));
    float4 bv = *(const float4*)(be + (lane << 2));
    float4 y;
    y.x = dx * rs * gv.x + bv.x;
    y.y = dy * rs * gv.y + bv.y;
    y.z = dz * rs * gv.z + bv.z;
    y.w = dw * rs * gv.w + bv.w;
    *(float4*)(outp + row * C1 + (lane << 2)) = y;
}

extern "C" void kernel_launch(void* const* d_in, const int* in_sizes, int n_in,
                              void* d_out, int out_size, void* d_ws, size_t ws_size,
                              hipStream_t stream) {
    const float* x    = (const float*)d_in[0];
    const float* emb  = (const float*)d_in[1];
    const float* w1l  = (const float*)d_in[2];
    const float* b1l  = (const float*)d_in[3];
    const float* w1r  = (const float*)d_in[4];
    const float* b1r  = (const float*)d_in[5];
    const float* att1 = (const float*)d_in[6];
    const float* bia1 = (const float*)d_in[7];
    const float* g1   = (const float*)d_in[8];
    const float* be1  = (const float*)d_in[9];
    const float* w2l  = (const float*)d_in[10];
    const float* b2l  = (const float*)d_in[11];
    const float* w2r  = (const float*)d_in[12];
    const float* b2r  = (const float*)d_in[13];
    const float* att2 = (const float*)d_in[14];
    const float* bia2 = (const float*)d_in[15];
    const float* g2   = (const float*)d_in[16];
    const float* be2  = (const float*)d_in[17];

    char* w = (char*)d_ws;
    float* xl    = (float*)w; w += (size_t)BB * NN * C1 * 4;
    float* xr    = (float*)w; w += (size_t)BB * NN * C1 * 4;
    float* ho    = (float*)w; w += (size_t)BB * NN * C1 * 4;
    u64* mask64  = (u64*)w;   w += (size_t)NN * 8 * 8;
    float* sl    = (float*)w; w += (size_t)HH * BB * NN * 4;
    float* sr    = (float*)w; w += (size_t)HH * BB * NN * 4;

    mask_k<<<dim3(NN / 16, 4), 256, 0, stream>>>(emb, mask64);
    proj1_k<<<dim3(BB * NN / 4, 4), 256, 0, stream>>>(x, w1l, b1l, w1r, b1r, att1, xl, xr, sl, sr);
    attn_k<<<dim3(NN / TI, HH, BB), 256, 0, stream>>>(xl, xr, att1, bia1, mask64, sl, sr, ho);
    projln_k<<<dim3(BB * NN / 4, 4), 256, 0, stream>>>(ho, g1, be1, w2l, b2l, w2r, b2r, att2, xl, xr, sl, sr);
    attn_k<<<dim3(NN / TI, HH, BB), 256, 0, stream>>>(xl, xr, att2, bia2, mask64, sl, sr, ho);
    ln2_k<<<BB * NN / 4, 256, 0, stream>>>(ho, g2, be2, (float*)d_out);
}